// Round 1
// baseline (1086.208 us; speedup 1.0000x reference)
//
#include <hip/hip_runtime.h>
#include <math.h>

// ---------------------------------------------------------------------------
// SelectiveSSM (Mamba block) fp32 baseline for MI355X.
// D_MODEL=1024, D_STATE=16, D_CONV=4, D_INNER=2048, DT_RANK=64, B=2, L=2048.
// BL = B*L = 4096 rows.
//
// ws layout (floats):
//   xz    : 4096*4096  = 16,777,216   (xi_raw cols 0..2047 | z cols 2048..4095)
//   xi    : 4096*2048  =  8,388,608   (post conv+silu)
//   xdbl  : 4096*96    =    393,216   (dt_lin 0..63 | B 64..79 | C 80..95)
//   dtyg  : 4096*2048  =  8,388,608   (dt after softplus; overwritten by y*silu(z) in pass3)
//   A2    : 2048*16    =     32,768   (-exp(A_log))
//   cP    : 2*2048*32*16 = 2,097,152  (per-chunk prod of dA)
//   cH    : 2*2048*32*16 = 2,097,152  (per-chunk local final h; becomes h_in after pass2)
// total ≈ 152.7 MB
// ---------------------------------------------------------------------------

#define D_INNER 2048
#define D_STATE 16
#define SEQLEN  2048
#define NBATCH  2
#define NCHUNK  32
#define CHUNKLEN (SEQLEN / NCHUNK)   // 64

__device__ __forceinline__ float siluf(float x) {
  return x / (1.f + __expf(-x));
}
__device__ __forceinline__ float softplusf(float x) {
  // log1p(exp(x)), overflow-stable; matches jax.nn.softplus in fp32
  return fmaxf(x, 0.f) + log1pf(__expf(-fabsf(x)));
}

// ---------------------------------------------------------------------------
// Generic fp32 GEMM: C[M,N] = A[M,K(lda)] @ B[K,N(ldb)], tiles 128x128x16,
// 256 threads, 8x8 per thread as 4 quadrants of 4x4 (bank-conflict-friendly).
// EPI==1: C = softplus(acc + bias[col]).
// Requires M%128==0, N%128==0, K%16==0.
// ---------------------------------------------------------------------------
template <int EPI>
__global__ __launch_bounds__(256, 2) void sgemm_k(
    const float* __restrict__ A, const float* __restrict__ B,
    const float* __restrict__ bias, float* __restrict__ C,
    int M, int N, int K, int lda, int ldb, int ldc)
{
  __shared__ float As[16][132];   // transposed A tile, padded (+4) for banks
  __shared__ float Bs[16][128];

  const int tid = threadIdx.x;
  const int m0 = blockIdx.y * 128;
  const int n0 = blockIdx.x * 128;
  const int tx = tid & 15;        // col group
  const int ty = tid >> 4;        // row group

  float acc[2][2][4][4];
#pragma unroll
  for (int a = 0; a < 2; a++)
#pragma unroll
    for (int b2 = 0; b2 < 2; b2++)
#pragma unroll
      for (int i = 0; i < 4; i++)
#pragma unroll
        for (int j = 0; j < 4; j++) acc[a][b2][i][j] = 0.f;

  for (int k0 = 0; k0 < K; k0 += 16) {
    // A tile: 128 rows x 16 k  -> As[k][row]
#pragma unroll
    for (int t = 0; t < 2; ++t) {
      int i = tid + t * 256;
      int row = i >> 2;
      int kq = (i & 3) * 4;
      float4 v = *(const float4*)(A + (size_t)(m0 + row) * lda + k0 + kq);
      As[kq + 0][row] = v.x; As[kq + 1][row] = v.y;
      As[kq + 2][row] = v.z; As[kq + 3][row] = v.w;
    }
    // B tile: 16 k x 128 cols -> Bs[k][col]
#pragma unroll
    for (int t = 0; t < 2; ++t) {
      int i = tid + t * 256;
      int kr = i >> 5;
      int cq = (i & 31) * 4;
      *(float4*)&Bs[kr][cq] = *(const float4*)(B + (size_t)(k0 + kr) * ldb + n0 + cq);
    }
    __syncthreads();
#pragma unroll
    for (int kk = 0; kk < 16; ++kk) {
      float4 a0 = *(const float4*)&As[kk][ty * 4];
      float4 a1 = *(const float4*)&As[kk][64 + ty * 4];
      float4 b0 = *(const float4*)&Bs[kk][tx * 4];
      float4 b1 = *(const float4*)&Bs[kk][64 + tx * 4];
      float av[2][4] = {{a0.x, a0.y, a0.z, a0.w}, {a1.x, a1.y, a1.z, a1.w}};
      float bv[2][4] = {{b0.x, b0.y, b0.z, b0.w}, {b1.x, b1.y, b1.z, b1.w}};
#pragma unroll
      for (int a = 0; a < 2; a++)
#pragma unroll
        for (int i = 0; i < 4; i++)
#pragma unroll
          for (int b2 = 0; b2 < 2; b2++)
#pragma unroll
            for (int j = 0; j < 4; j++)
              acc[a][b2][i][j] = fmaf(av[a][i], bv[b2][j], acc[a][b2][i][j]);
    }
    __syncthreads();
  }

#pragma unroll
  for (int a = 0; a < 2; a++) {
#pragma unroll
    for (int i = 0; i < 4; i++) {
      int row = m0 + a * 64 + ty * 4 + i;
#pragma unroll
      for (int b2 = 0; b2 < 2; b2++) {
        int col = n0 + b2 * 64 + tx * 4;
        float4 v = make_float4(acc[a][b2][i][0], acc[a][b2][i][1],
                               acc[a][b2][i][2], acc[a][b2][i][3]);
        if (EPI == 1) {
          v.x = softplusf(v.x + bias[col + 0]);
          v.y = softplusf(v.y + bias[col + 1]);
          v.z = softplusf(v.z + bias[col + 2]);
          v.w = softplusf(v.w + bias[col + 3]);
        }
        *(float4*)(C + (size_t)row * ldc + col) = v;
      }
    }
  }
}

// ---------------------------------------------------------------------------
// depthwise causal conv1d (taps=4, left-pad 3) + bias + silu
// one thread per (row, d); reads xi_raw columns of xz; writes xi.
// ---------------------------------------------------------------------------
__global__ __launch_bounds__(256) void conv_silu_k(
    const float* __restrict__ xz, const float* __restrict__ cw,
    const float* __restrict__ cb, float* __restrict__ xi)
{
  int idx = blockIdx.x * 256 + threadIdx.x;   // row*2048 + d
  int d = idx & (D_INNER - 1);
  int row = idx >> 11;                        // b*L + l
  int l = row & (SEQLEN - 1);
  float4 w = *(const float4*)(cw + d * 4);
  const float wv[4] = {w.x, w.y, w.z, w.w};
  float acc = cb[d];
#pragma unroll
  for (int j = 0; j < 4; j++) {
    int ll = l - 3 + j;
    if (ll >= 0)
      acc = fmaf(wv[j], xz[(size_t)(row - 3 + j) * 4096 + d], acc);
  }
  xi[idx] = siluf(acc);
}

// ---------------------------------------------------------------------------
// x_dbl = xi(4096x2048) @ W_x(2048x96), split-K (8 chunks of 256) + atomics.
// block: 64 rows x 96 cols; thread = 2 rows x 12 cols.
// ---------------------------------------------------------------------------
__global__ __launch_bounds__(256) void xdbl_k(
    const float* __restrict__ xi, const float* __restrict__ Wx,
    float* __restrict__ xdbl)
{
  __shared__ float Xs[32][66];   // [k][row], padded
  __shared__ float Ws[32][96];

  const int tid = threadIdx.x;
  const int r0 = blockIdx.x * 64;
  const int k0 = blockIdx.y * 256;
  const int rowg = tid >> 3;     // 0..31 -> rows rowg*2 + {0,1}
  const int colg = tid & 7;      // 0..7  -> cols colg*12 .. +11

  float acc[2][12];
#pragma unroll
  for (int i = 0; i < 2; i++)
#pragma unroll
    for (int j = 0; j < 12; j++) acc[i][j] = 0.f;

  for (int kc = 0; kc < 256; kc += 32) {
    int kbase = k0 + kc;
#pragma unroll
    for (int t = 0; t < 2; t++) {
      int i = tid + t * 256;
      int row = i >> 3;
      int kq = (i & 7) * 4;
      float4 v = *(const float4*)(xi + (size_t)(r0 + row) * 2048 + kbase + kq);
      Xs[kq + 0][row] = v.x; Xs[kq + 1][row] = v.y;
      Xs[kq + 2][row] = v.z; Xs[kq + 3][row] = v.w;
    }
#pragma unroll
    for (int t = 0; t < 3; t++) {
      int i = tid + t * 256;     // 0..767 ; 24 float4 per k-row
      int kr = i / 24;
      int cq = (i % 24) * 4;
      *(float4*)&Ws[kr][cq] = *(const float4*)(Wx + (size_t)(kbase + kr) * 96 + cq);
    }
    __syncthreads();
#pragma unroll
    for (int kk = 0; kk < 32; kk++) {
      float2 a = *(const float2*)&Xs[kk][rowg * 2];
      float4 b0 = *(const float4*)&Ws[kk][colg * 12];
      float4 b1 = *(const float4*)&Ws[kk][colg * 12 + 4];
      float4 b2 = *(const float4*)&Ws[kk][colg * 12 + 8];
      float bv[12] = {b0.x, b0.y, b0.z, b0.w, b1.x, b1.y, b1.z, b1.w,
                      b2.x, b2.y, b2.z, b2.w};
#pragma unroll
      for (int j = 0; j < 12; j++) {
        acc[0][j] = fmaf(a.x, bv[j], acc[0][j]);
        acc[1][j] = fmaf(a.y, bv[j], acc[1][j]);
      }
    }
    __syncthreads();
  }
#pragma unroll
  for (int i = 0; i < 2; i++) {
    int row = r0 + rowg * 2 + i;
#pragma unroll
    for (int j = 0; j < 12; j++)
      atomicAdd(&xdbl[(size_t)row * 96 + colg * 12 + j], acc[i][j]);
  }
}

// ---------------------------------------------------------------------------
// A2 = -exp(A_log)
// ---------------------------------------------------------------------------
__global__ __launch_bounds__(256) void aprep_k(const float* __restrict__ A_log,
                                               float* __restrict__ A2)
{
  int i = blockIdx.x * 256 + threadIdx.x;
  A2[i] = -__expf(A_log[i]);
}

// ---------------------------------------------------------------------------
// scan pass 1: per (b, chunk, d) compute P = prod(dA), h_local (h0=0)
// ---------------------------------------------------------------------------
__global__ __launch_bounds__(256) void scan_pass1(
    const float* __restrict__ dt, const float* __restrict__ xi,
    const float* __restrict__ xdbl, const float* __restrict__ A2,
    float* __restrict__ cP, float* __restrict__ cH)
{
  int d = blockIdx.x * 256 + threadIdx.x;
  int c = blockIdx.y;
  int b = blockIdx.z;
  float a2[D_STATE], h[D_STATE], P[D_STATE];
#pragma unroll
  for (int n = 0; n < D_STATE; n++) {
    a2[n] = A2[d * D_STATE + n];
    h[n] = 0.f;
    P[n] = 1.f;
  }
  int rowbase = b * SEQLEN + c * CHUNKLEN;
  for (int l = 0; l < CHUNKLEN; l++) {
    int row = rowbase + l;
    float dtv = dt[(size_t)row * D_INNER + d];
    float xv = xi[(size_t)row * D_INNER + d];
    float dtx = dtv * xv;
    const float* Bp = xdbl + (size_t)row * 96 + 64;   // wave-uniform -> s_load
#pragma unroll
    for (int n = 0; n < D_STATE; n++) {
      float dA = __expf(dtv * a2[n]);
      P[n] *= dA;
      h[n] = fmaf(dA, h[n], dtx * Bp[n]);
    }
  }
  size_t base = ((size_t)(b * D_INNER + d) * NCHUNK + c) * D_STATE;
#pragma unroll
  for (int n = 0; n < D_STATE; n++) {
    cP[base + n] = P[n];
    cH[base + n] = h[n];
  }
}

// ---------------------------------------------------------------------------
// scan pass 2: sequential over chunks per (b,d,n); overwrites cH with h_in.
// ---------------------------------------------------------------------------
__global__ __launch_bounds__(256) void scan_pass2(
    const float* __restrict__ cP, float* __restrict__ cH)
{
  int t = blockIdx.x * 256 + threadIdx.x;   // (b*2048+d)*16 + n
  size_t base = (size_t)(t >> 4) * (NCHUNK * D_STATE) + (t & 15);
  float h = 0.f;
  for (int c = 0; c < NCHUNK; c++) {
    size_t idx = base + (size_t)c * D_STATE;
    float Pv = cP[idx];
    float q = cH[idx];
    cH[idx] = h;             // h_in for this chunk
    h = fmaf(Pv, h, q);
  }
}

// ---------------------------------------------------------------------------
// scan pass 3: replay chunk with correct h_in, y = h.C + D*x, fuse y*silu(z);
// writes yg IN-PLACE over dt (each element read by exactly this thread first).
// ---------------------------------------------------------------------------
__global__ __launch_bounds__(256) void scan_pass3(
    float* __restrict__ dtyg, const float* __restrict__ xi,
    const float* __restrict__ xdbl, const float* __restrict__ A2,
    const float* __restrict__ cH, const float* __restrict__ Dvec,
    const float* __restrict__ xz)
{
  int d = blockIdx.x * 256 + threadIdx.x;
  int c = blockIdx.y;
  int b = blockIdx.z;
  float a2[D_STATE], h[D_STATE];
  size_t base = ((size_t)(b * D_INNER + d) * NCHUNK + c) * D_STATE;
#pragma unroll
  for (int n = 0; n < D_STATE; n++) {
    a2[n] = A2[d * D_STATE + n];
    h[n] = cH[base + n];
  }
  float Dd = Dvec[d];
  int rowbase = b * SEQLEN + c * CHUNKLEN;
  for (int l = 0; l < CHUNKLEN; l++) {
    int row = rowbase + l;
    float dtv = dtyg[(size_t)row * D_INNER + d];
    float xv = xi[(size_t)row * D_INNER + d];
    float dtx = dtv * xv;
    const float* Bp = xdbl + (size_t)row * 96 + 64;
    const float* Cp = Bp + D_STATE;
    float y = Dd * xv;
#pragma unroll
    for (int n = 0; n < D_STATE; n++) {
      float dA = __expf(dtv * a2[n]);
      h[n] = fmaf(dA, h[n], dtx * Bp[n]);
      y = fmaf(h[n], Cp[n], y);
    }
    float z = xz[(size_t)row * 4096 + D_INNER + d];
    dtyg[(size_t)row * D_INNER + d] = y * siluf(z);
  }
}

// ---------------------------------------------------------------------------
extern "C" void kernel_launch(void* const* d_in, const int* in_sizes, int n_in,
                              void* d_out, int out_size, void* d_ws,
                              size_t ws_size, hipStream_t stream)
{
  const float* x     = (const float*)d_in[0];
  const float* W_in  = (const float*)d_in[1];
  const float* cw    = (const float*)d_in[2];
  const float* cb    = (const float*)d_in[3];
  const float* W_x   = (const float*)d_in[4];
  const float* W_dt  = (const float*)d_in[5];
  const float* b_dt  = (const float*)d_in[6];
  const float* A_log = (const float*)d_in[7];
  const float* Dv    = (const float*)d_in[8];
  const float* W_out = (const float*)d_in[9];
  float* out = (float*)d_out;

  float* ws   = (float*)d_ws;
  float* xz   = ws;                       // 16,777,216
  float* xi   = xz + 16777216;            //  8,388,608
  float* xdbl = xi + 8388608;             //    393,216
  float* dtyg = xdbl + 393216;            //  8,388,608
  float* A2   = dtyg + 8388608;           //     32,768
  float* cP   = A2 + 32768;               //  2,097,152
  float* cH   = cP + 2097152;             //  2,097,152

  // x_dbl is accumulated with atomics -> zero it every launch (ws re-poisoned)
  hipMemsetAsync(xdbl, 0, 393216 * sizeof(float), stream);

  aprep_k<<<128, 256, 0, stream>>>(A_log, A2);

  // xz = x @ W_in  (4096x1024 @ 1024x4096)
  sgemm_k<0><<<dim3(32, 32), 256, 0, stream>>>(x, W_in, nullptr, xz,
                                               4096, 4096, 1024, 1024, 4096, 4096);
  // conv + silu -> xi
  conv_silu_k<<<32768, 256, 0, stream>>>(xz, cw, cb, xi);

  // x_dbl = xi @ W_x (split-K, atomics)
  xdbl_k<<<dim3(64, 8), 256, 0, stream>>>(xi, W_x, xdbl);

  // dt = softplus(x_dbl[:, :64] @ W_dt + b_dt)  (4096x64 @ 64x2048)
  sgemm_k<1><<<dim3(16, 32), 256, 0, stream>>>(xdbl, W_dt, b_dt, dtyg,
                                               4096, 2048, 64, 96, 2048, 2048);

  // chunked selective scan
  scan_pass1<<<dim3(8, NCHUNK, NBATCH), 256, 0, stream>>>(dtyg, xi, xdbl, A2, cP, cH);
  scan_pass2<<<256, 256, 0, stream>>>(cP, cH);
  scan_pass3<<<dim3(8, NCHUNK, NBATCH), 256, 0, stream>>>(dtyg, xi, xdbl, A2, cH, Dv, xz);

  // out = yg @ W_out  (4096x2048 @ 2048x1024)
  sgemm_k<0><<<dim3(8, 32), 256, 0, stream>>>(dtyg, W_out, nullptr, out,
                                              4096, 1024, 2048, 2048, 1024, 1024);
}

// Round 3
// 681.554 us; speedup vs baseline: 1.5937x; 1.5937x over previous
//
#include <hip/hip_runtime.h>
#include <math.h>

// ---------------------------------------------------------------------------
// SelectiveSSM (Mamba block) for MI355X — round 2 (resubmit): big GEMMs on
// MFMA via split-bf16 (hi/lo) with fp32 accumulate.
//
// ws layout (floats):
//   xz    : 16,777,216   (xi_raw 0..2047 | z 2048..4095)
//   xi    :  8,388,608
//   xdbl  :    393,216   (dt_lin 0..63 | B 64..79 | C 80..95)
//   dtyg  :  8,388,608   (holds W_inT first, then dt, then y*silu(z))
//   A2    :     32,768
//   cP    :  2,097,152   (scan chunk-products; reused as WoutT after pass2)
//   cH    :  2,097,152
// total ≈ 152.7 MB  (same as verified round-0 layout)
// ---------------------------------------------------------------------------

#define D_INNER 2048
#define D_STATE 16
#define SEQLEN  2048
#define NBATCH  2
#define NCHUNK  32
#define CHUNKLEN (SEQLEN / NCHUNK)   // 64

using f32x4 = __attribute__((ext_vector_type(4))) float;
using s16x8 = __attribute__((ext_vector_type(8))) short;

__device__ __forceinline__ float siluf(float x) {
  return x / (1.f + __expf(-x));
}
__device__ __forceinline__ float softplusf(float x) {
  return fmaxf(x, 0.f) + log1pf(__expf(-fabsf(x)));
}

// ---------------------------------------------------------------------------
// fp32 -> (hi,lo) bf16 split of 8 floats.  hi = truncate-to-bf16 (exact
// residual), lo = RNE-bf16(residual).  a ≈ hi + lo with ~2^-17 rel error.
// ---------------------------------------------------------------------------
union FragU { unsigned int u[4]; s16x8 v; };

__device__ __forceinline__ void cvt_split8(const float* f, s16x8& hi, s16x8& lo) {
  FragU H, L;
#pragma unroll
  for (int p = 0; p < 4; ++p) {
    unsigned int b0 = __float_as_uint(f[2 * p]);
    unsigned int b1 = __float_as_uint(f[2 * p + 1]);
    H.u[p] = (b0 >> 16) | (b1 & 0xFFFF0000u);
    float r0 = f[2 * p]     - __uint_as_float(b0 & 0xFFFF0000u);
    float r1 = f[2 * p + 1] - __uint_as_float(b1 & 0xFFFF0000u);
    unsigned int c0 = __float_as_uint(r0); c0 += 0x7FFFu + ((c0 >> 16) & 1u);
    unsigned int c1 = __float_as_uint(r1); c1 += 0x7FFFu + ((c1 >> 16) & 1u);
    L.u[p] = (c0 >> 16) | (c1 & 0xFFFF0000u);
  }
  hi = H.v; lo = L.v;
}

// ---------------------------------------------------------------------------
// Split-bf16 MFMA GEMM: C[M,N] = A[M,K] @ Bt[N,K]^T (both operands k-major).
// 128x128 tile, BK=32, 4 waves (each 64x64 = 4x4 frags of 16x16x32).
// fp32 tiles staged to LDS via global_load_lds with XOR-swizzled SOURCE
// (16B slot ^ (row&7)) so the stride-128B fragment reads are conflict-light
// (G4 pattern); hi/lo conversion happens on the read side (registers).
// Requires M%128==0, N%128==0, K%32==0.
// ---------------------------------------------------------------------------
__global__ __launch_bounds__(256, 2) void mgemm_split(
    const float* __restrict__ A, const float* __restrict__ Bt,
    float* __restrict__ C, int M, int N, int K, int lda, int ldb, int ldc)
{
  __shared__ float As[128 * 32];   // 16 KB, row-major [128][32], swizzled slots
  __shared__ float Bs[128 * 32];   // 16 KB

  const int tid = threadIdx.x;
  const int wv  = tid >> 6;
  const int ln  = tid & 63;
  const int wr  = wv >> 1, wc = wv & 1;
  const int m0  = blockIdx.y * 128, n0 = blockIdx.x * 128;

  const int ko = ln >> 4;          // k-group 0..3 (8 k each)
  const int rr = ln & 15;          // row/col within 16-frag
  const int s0 = (2 * ko)     ^ (rr & 7);   // swizzled 16B slot of k-half 0
  const int s1 = (2 * ko + 1) ^ (rr & 7);   // ... k-half 1

  // staging: wave wv issues instrs i = wv*4+t; each covers 8 rows x 32 floats
  const int srow  = ln >> 3;              // row within 8-row group (0..7)
  const int sslot = (ln & 7) ^ srow;      // pre-swizzled global k-slot

  f32x4 acc[4][4];
#pragma unroll
  for (int i = 0; i < 4; i++)
#pragma unroll
    for (int j = 0; j < 4; j++) acc[i][j] = (f32x4)0.f;

  for (int kt = 0; kt < K; kt += 32) {
    __syncthreads();   // prior tile's reads done before overwrite
#pragma unroll
    for (int t = 0; t < 4; ++t) {
      int i = wv * 4 + t;
      const float* ga = A  + (size_t)(m0 + i * 8 + srow) * lda + kt + sslot * 4;
      const float* gb = Bt + (size_t)(n0 + i * 8 + srow) * ldb + kt + sslot * 4;
      __builtin_amdgcn_global_load_lds(
          (const __attribute__((address_space(1))) void*)ga,
          (__attribute__((address_space(3))) void*)(As + i * 256), 16, 0, 0);
      __builtin_amdgcn_global_load_lds(
          (const __attribute__((address_space(1))) void*)gb,
          (__attribute__((address_space(3))) void*)(Bs + i * 256), 16, 0, 0);
    }
    __syncthreads();   // compiler emits vmcnt(0) drain before barrier

    s16x8 ah[4], al[4], bh[4], bl[4];
#pragma unroll
    for (int mi = 0; mi < 4; ++mi) {
      int r = wr * 64 + mi * 16 + rr;
      float f[8];
      *(float4*)&f[0] = *(const float4*)(As + r * 32 + s0 * 4);
      *(float4*)&f[4] = *(const float4*)(As + r * 32 + s1 * 4);
      cvt_split8(f, ah[mi], al[mi]);
    }
#pragma unroll
    for (int ni = 0; ni < 4; ++ni) {
      int c = wc * 64 + ni * 16 + rr;
      float f[8];
      *(float4*)&f[0] = *(const float4*)(Bs + c * 32 + s0 * 4);
      *(float4*)&f[4] = *(const float4*)(Bs + c * 32 + s1 * 4);
      cvt_split8(f, bh[ni], bl[ni]);
    }
#pragma unroll
    for (int mi = 0; mi < 4; ++mi)
#pragma unroll
      for (int ni = 0; ni < 4; ++ni) {
        acc[mi][ni] = __builtin_amdgcn_mfma_f32_16x16x32_bf16(ah[mi], bh[ni], acc[mi][ni], 0, 0, 0);
        acc[mi][ni] = __builtin_amdgcn_mfma_f32_16x16x32_bf16(ah[mi], bl[ni], acc[mi][ni], 0, 0, 0);
        acc[mi][ni] = __builtin_amdgcn_mfma_f32_16x16x32_bf16(al[mi], bh[ni], acc[mi][ni], 0, 0, 0);
      }
  }

  // epilogue: D row = (ln>>4)*4 + i, col = ln&15  (m89-verified mapping)
  const int orow = (ln >> 4) * 4;
#pragma unroll
  for (int mi = 0; mi < 4; ++mi)
#pragma unroll
    for (int ni = 0; ni < 4; ++ni) {
      int rowg = m0 + wr * 64 + mi * 16 + orow;
      int colg = n0 + wc * 64 + ni * 16 + rr;
#pragma unroll
      for (int i = 0; i < 4; ++i)
        C[(size_t)(rowg + i) * ldc + colg] = acc[mi][ni][i];
    }
}

// ---------------------------------------------------------------------------
// 32x32 tiled transpose: out[C][R] = in[R][C]^T   (weights, once per launch)
// ---------------------------------------------------------------------------
__global__ __launch_bounds__(256) void transpose_k(
    const float* __restrict__ in, float* __restrict__ out, int R, int C)
{
  __shared__ float t[32][33];
  int bx = blockIdx.x * 32;   // col base
  int by = blockIdx.y * 32;   // row base
  int lx = threadIdx.x & 31, ly = threadIdx.x >> 5;
#pragma unroll
  for (int i = 0; i < 32; i += 8)
    t[ly + i][lx] = in[(size_t)(by + ly + i) * C + bx + lx];
  __syncthreads();
#pragma unroll
  for (int i = 0; i < 32; i += 8)
    out[(size_t)(bx + ly + i) * R + by + lx] = t[lx][ly + i];
}

// ---------------------------------------------------------------------------
// fp32 GEMM (kept for the small K=64 dt projection), 128x128x16 tiles.
// EPI==1: C = softplus(acc + bias[col]).
// ---------------------------------------------------------------------------
template <int EPI>
__global__ __launch_bounds__(256, 2) void sgemm_k(
    const float* __restrict__ A, const float* __restrict__ B,
    const float* __restrict__ bias, float* __restrict__ C,
    int M, int N, int K, int lda, int ldb, int ldc)
{
  __shared__ float As[16][132];
  __shared__ float Bs[16][128];

  const int tid = threadIdx.x;
  const int m0 = blockIdx.y * 128;
  const int n0 = blockIdx.x * 128;
  const int tx = tid & 15;
  const int ty = tid >> 4;

  float acc[2][2][4][4];
#pragma unroll
  for (int a = 0; a < 2; a++)
#pragma unroll
    for (int b2 = 0; b2 < 2; b2++)
#pragma unroll
      for (int i = 0; i < 4; i++)
#pragma unroll
        for (int j = 0; j < 4; j++) acc[a][b2][i][j] = 0.f;

  for (int k0 = 0; k0 < K; k0 += 16) {
#pragma unroll
    for (int t = 0; t < 2; ++t) {
      int i = tid + t * 256;
      int row = i >> 2;
      int kq = (i & 3) * 4;
      float4 v = *(const float4*)(A + (size_t)(m0 + row) * lda + k0 + kq);
      As[kq + 0][row] = v.x; As[kq + 1][row] = v.y;
      As[kq + 2][row] = v.z; As[kq + 3][row] = v.w;
    }
#pragma unroll
    for (int t = 0; t < 2; ++t) {
      int i = tid + t * 256;
      int kr = i >> 5;
      int cq = (i & 31) * 4;
      *(float4*)&Bs[kr][cq] = *(const float4*)(B + (size_t)(k0 + kr) * ldb + n0 + cq);
    }
    __syncthreads();
#pragma unroll
    for (int kk = 0; kk < 16; ++kk) {
      float4 a0 = *(const float4*)&As[kk][ty * 4];
      float4 a1 = *(const float4*)&As[kk][64 + ty * 4];
      float4 b0 = *(const float4*)&Bs[kk][tx * 4];
      float4 b1 = *(const float4*)&Bs[kk][64 + tx * 4];
      float av[2][4] = {{a0.x, a0.y, a0.z, a0.w}, {a1.x, a1.y, a1.z, a1.w}};
      float bv[2][4] = {{b0.x, b0.y, b0.z, b0.w}, {b1.x, b1.y, b1.z, b1.w}};
#pragma unroll
      for (int a = 0; a < 2; a++)
#pragma unroll
        for (int i = 0; i < 4; i++)
#pragma unroll
          for (int b2 = 0; b2 < 2; b2++)
#pragma unroll
            for (int j = 0; j < 4; j++)
              acc[a][b2][i][j] = fmaf(av[a][i], bv[b2][j], acc[a][b2][i][j]);
    }
    __syncthreads();
  }

#pragma unroll
  for (int a = 0; a < 2; a++) {
#pragma unroll
    for (int i = 0; i < 4; i++) {
      int row = m0 + a * 64 + ty * 4 + i;
#pragma unroll
      for (int b2 = 0; b2 < 2; b2++) {
        int col = n0 + b2 * 64 + tx * 4;
        float4 v = make_float4(acc[a][b2][i][0], acc[a][b2][i][1],
                               acc[a][b2][i][2], acc[a][b2][i][3]);
        if (EPI == 1) {
          v.x = softplusf(v.x + bias[col + 0]);
          v.y = softplusf(v.y + bias[col + 1]);
          v.z = softplusf(v.z + bias[col + 2]);
          v.w = softplusf(v.w + bias[col + 3]);
        }
        *(float4*)(C + (size_t)row * ldc + col) = v;
      }
    }
  }
}

// ---------------------------------------------------------------------------
// depthwise causal conv1d (taps=4) + bias + silu
// ---------------------------------------------------------------------------
__global__ __launch_bounds__(256) void conv_silu_k(
    const float* __restrict__ xz, const float* __restrict__ cw,
    const float* __restrict__ cb, float* __restrict__ xi)
{
  int idx = blockIdx.x * 256 + threadIdx.x;
  int d = idx & (D_INNER - 1);
  int row = idx >> 11;
  int l = row & (SEQLEN - 1);
  float4 w = *(const float4*)(cw + d * 4);
  const float wv[4] = {w.x, w.y, w.z, w.w};
  float acc = cb[d];
#pragma unroll
  for (int j = 0; j < 4; j++) {
    int ll = l - 3 + j;
    if (ll >= 0)
      acc = fmaf(wv[j], xz[(size_t)(row - 3 + j) * 4096 + d], acc);
  }
  xi[idx] = siluf(acc);
}

// ---------------------------------------------------------------------------
// x_dbl = xi(4096x2048) @ W_x(2048x96), split-K + atomics.
// ---------------------------------------------------------------------------
__global__ __launch_bounds__(256) void xdbl_k(
    const float* __restrict__ xi, const float* __restrict__ Wx,
    float* __restrict__ xdbl)
{
  __shared__ float Xs[32][66];
  __shared__ float Ws[32][96];

  const int tid = threadIdx.x;
  const int r0 = blockIdx.x * 64;
  const int k0 = blockIdx.y * 256;
  const int rowg = tid >> 3;
  const int colg = tid & 7;

  float acc[2][12];
#pragma unroll
  for (int i = 0; i < 2; i++)
#pragma unroll
    for (int j = 0; j < 12; j++) acc[i][j] = 0.f;

  for (int kc = 0; kc < 256; kc += 32) {
    int kbase = k0 + kc;
#pragma unroll
    for (int t = 0; t < 2; t++) {
      int i = tid + t * 256;
      int row = i >> 3;
      int kq = (i & 7) * 4;
      float4 v = *(const float4*)(xi + (size_t)(r0 + row) * 2048 + kbase + kq);
      Xs[kq + 0][row] = v.x; Xs[kq + 1][row] = v.y;
      Xs[kq + 2][row] = v.z; Xs[kq + 3][row] = v.w;
    }
#pragma unroll
    for (int t = 0; t < 3; t++) {
      int i = tid + t * 256;
      int kr = i / 24;
      int cq = (i % 24) * 4;
      *(float4*)&Ws[kr][cq] = *(const float4*)(Wx + (size_t)(kbase + kr) * 96 + cq);
    }
    __syncthreads();
#pragma unroll
    for (int kk = 0; kk < 32; kk++) {
      float2 a = *(const float2*)&Xs[kk][rowg * 2];
      float4 b0 = *(const float4*)&Ws[kk][colg * 12];
      float4 b1 = *(const float4*)&Ws[kk][colg * 12 + 4];
      float4 b2 = *(const float4*)&Ws[kk][colg * 12 + 8];
      float bv[12] = {b0.x, b0.y, b0.z, b0.w, b1.x, b1.y, b1.z, b1.w,
                      b2.x, b2.y, b2.z, b2.w};
#pragma unroll
      for (int j = 0; j < 12; j++) {
        acc[0][j] = fmaf(a.x, bv[j], acc[0][j]);
        acc[1][j] = fmaf(a.y, bv[j], acc[1][j]);
      }
    }
    __syncthreads();
  }
#pragma unroll
  for (int i = 0; i < 2; i++) {
    int row = r0 + rowg * 2 + i;
#pragma unroll
    for (int j = 0; j < 12; j++)
      atomicAdd(&xdbl[(size_t)row * 96 + colg * 12 + j], acc[i][j]);
  }
}

__global__ __launch_bounds__(256) void aprep_k(const float* __restrict__ A_log,
                                               float* __restrict__ A2)
{
  int i = blockIdx.x * 256 + threadIdx.x;
  A2[i] = -__expf(A_log[i]);
}

// ---------------------------------------------------------------------------
// chunked selective scan (3 passes) — unchanged
// ---------------------------------------------------------------------------
__global__ __launch_bounds__(256) void scan_pass1(
    const float* __restrict__ dt, const float* __restrict__ xi,
    const float* __restrict__ xdbl, const float* __restrict__ A2,
    float* __restrict__ cP, float* __restrict__ cH)
{
  int d = blockIdx.x * 256 + threadIdx.x;
  int c = blockIdx.y;
  int b = blockIdx.z;
  float a2[D_STATE], h[D_STATE], P[D_STATE];
#pragma unroll
  for (int n = 0; n < D_STATE; n++) {
    a2[n] = A2[d * D_STATE + n];
    h[n] = 0.f;
    P[n] = 1.f;
  }
  int rowbase = b * SEQLEN + c * CHUNKLEN;
  for (int l = 0; l < CHUNKLEN; l++) {
    int row = rowbase + l;
    float dtv = dt[(size_t)row * D_INNER + d];
    float xv = xi[(size_t)row * D_INNER + d];
    float dtx = dtv * xv;
    const float* Bp = xdbl + (size_t)row * 96 + 64;
#pragma unroll
    for (int n = 0; n < D_STATE; n++) {
      float dA = __expf(dtv * a2[n]);
      P[n] *= dA;
      h[n] = fmaf(dA, h[n], dtx * Bp[n]);
    }
  }
  size_t base = ((size_t)(b * D_INNER + d) * NCHUNK + c) * D_STATE;
#pragma unroll
  for (int n = 0; n < D_STATE; n++) {
    cP[base + n] = P[n];
    cH[base + n] = h[n];
  }
}

__global__ __launch_bounds__(256) void scan_pass2(
    const float* __restrict__ cP, float* __restrict__ cH)
{
  int t = blockIdx.x * 256 + threadIdx.x;
  size_t base = (size_t)(t >> 4) * (NCHUNK * D_STATE) + (t & 15);
  float h = 0.f;
  for (int c = 0; c < NCHUNK; c++) {
    size_t idx = base + (size_t)c * D_STATE;
    float Pv = cP[idx];
    float q = cH[idx];
    cH[idx] = h;
    h = fmaf(Pv, h, q);
  }
}

__global__ __launch_bounds__(256) void scan_pass3(
    float* __restrict__ dtyg, const float* __restrict__ xi,
    const float* __restrict__ xdbl, const float* __restrict__ A2,
    const float* __restrict__ cH, const float* __restrict__ Dvec,
    const float* __restrict__ xz)
{
  int d = blockIdx.x * 256 + threadIdx.x;
  int c = blockIdx.y;
  int b = blockIdx.z;
  float a2[D_STATE], h[D_STATE];
  size_t base = ((size_t)(b * D_INNER + d) * NCHUNK + c) * D_STATE;
#pragma unroll
  for (int n = 0; n < D_STATE; n++) {
    a2[n] = A2[d * D_STATE + n];
    h[n] = cH[base + n];
  }
  float Dd = Dvec[d];
  int rowbase = b * SEQLEN + c * CHUNKLEN;
  for (int l = 0; l < CHUNKLEN; l++) {
    int row = rowbase + l;
    float dtv = dtyg[(size_t)row * D_INNER + d];
    float xv = xi[(size_t)row * D_INNER + d];
    float dtx = dtv * xv;
    const float* Bp = xdbl + (size_t)row * 96 + 64;
    const float* Cp = Bp + D_STATE;
    float y = Dd * xv;
#pragma unroll
    for (int n = 0; n < D_STATE; n++) {
      float dA = __expf(dtv * a2[n]);
      h[n] = fmaf(dA, h[n], dtx * Bp[n]);
      y = fmaf(h[n], Cp[n], y);
    }
    float z = xz[(size_t)row * 4096 + D_INNER + d];
    dtyg[(size_t)row * D_INNER + d] = y * siluf(z);
  }
}

// ---------------------------------------------------------------------------
extern "C" void kernel_launch(void* const* d_in, const int* in_sizes, int n_in,
                              void* d_out, int out_size, void* d_ws,
                              size_t ws_size, hipStream_t stream)
{
  const float* x     = (const float*)d_in[0];
  const float* W_in  = (const float*)d_in[1];
  const float* cw    = (const float*)d_in[2];
  const float* cb    = (const float*)d_in[3];
  const float* W_x   = (const float*)d_in[4];
  const float* W_dt  = (const float*)d_in[5];
  const float* b_dt  = (const float*)d_in[6];
  const float* A_log = (const float*)d_in[7];
  const float* Dv    = (const float*)d_in[8];
  const float* W_out = (const float*)d_in[9];
  float* out = (float*)d_out;

  float* ws    = (float*)d_ws;
  float* xz    = ws;                       // 16,777,216
  float* xi    = xz + 16777216;            //  8,388,608
  float* xdbl  = xi + 8388608;             //    393,216
  float* dtyg  = xdbl + 393216;            //  8,388,608  (W_inT -> dt -> yg)
  float* A2    = dtyg + 8388608;           //     32,768
  float* cP    = A2 + 32768;               //  2,097,152  (later reused as WoutT)
  float* cH    = cP + 2097152;             //  2,097,152
  float* WinT  = dtyg;                     //  4,194,304 (overlaid, dead before dt-GEMM)
  float* WoutT = cP;                       //  2,097,152 (overlaid, cP dead after pass2)

  hipMemsetAsync(xdbl, 0, 393216 * sizeof(float), stream);
  aprep_k<<<128, 256, 0, stream>>>(A_log, A2);

  // W_in^T (k-major B operand for the first MFMA GEMM)
  transpose_k<<<dim3(128, 32), 256, 0, stream>>>(W_in, WinT, 1024, 4096);

  // xz = x @ W_in   (4096x1024 @ 1024x4096) via split-bf16 MFMA
  mgemm_split<<<dim3(32, 32), 256, 0, stream>>>(x, WinT, xz,
                                                4096, 4096, 1024, 1024, 1024, 4096);

  conv_silu_k<<<32768, 256, 0, stream>>>(xz, cw, cb, xi);

  xdbl_k<<<dim3(64, 8), 256, 0, stream>>>(xi, W_x, xdbl);

  // dt = softplus(x_dbl[:, :64] @ W_dt + b_dt)  (K=64, stays fp32)
  sgemm_k<1><<<dim3(16, 32), 256, 0, stream>>>(xdbl, W_dt, b_dt, dtyg,
                                               4096, 2048, 64, 96, 2048, 2048);

  scan_pass1<<<dim3(8, NCHUNK, NBATCH), 256, 0, stream>>>(dtyg, xi, xdbl, A2, cP, cH);
  scan_pass2<<<256, 256, 0, stream>>>(cP, cH);
  scan_pass3<<<dim3(8, NCHUNK, NBATCH), 256, 0, stream>>>(dtyg, xi, xdbl, A2, cH, Dv, xz);

  // W_out^T into cP's space (cP dead after pass2)
  transpose_k<<<dim3(32, 64), 256, 0, stream>>>(W_out, WoutT, 2048, 1024);

  // out = yg @ W_out  (4096x2048 @ 2048x1024) via split-bf16 MFMA
  mgemm_split<<<dim3(8, 32), 256, 0, stream>>>(dtyg, WoutT, out,
                                               4096, 1024, 2048, 2048, 2048, 1024);
}

// Round 4
// 623.905 us; speedup vs baseline: 1.7410x; 1.0924x over previous
//
#include <hip/hip_runtime.h>
#include <math.h>

// ---------------------------------------------------------------------------
// SelectiveSSM (Mamba block) for MI355X — round 4: pre-split hi/lo bf16
// operands (packed [row][K/32][32 hi | 32 lo]) so the MFMA GEMM loop has
// zero VALU conversion; bf16 LDS staging via global_load_lds with XOR
// slot-swizzle (s ^= row&7) -> bank-minimum ds_read_b128 fragment reads.
//
// ws layout (floats):
//   xz    : 16,777,216   (xi_raw 0..2047 | z 2048..4095)
//   xi    :  8,388,608   (post conv+silu; reused as ygP after pass3)
//   xdbl  :    393,216   (dt_lin 0..63 | B 64..79 | C 80..95)
//   dtyg  :  8,388,608   (WinTP[0:4M]+xP[4M:8M] first, then dt, then yg)
//   A2    :     32,768
//   cP    :  2,097,152   (scan chunk-products; reused as WoutTP after pass2)
//   cH    :  2,097,152
// total ≈ 152.7 MB (same as verified round-0 layout)
// ---------------------------------------------------------------------------

#define D_INNER 2048
#define D_STATE 16
#define SEQLEN  2048
#define NBATCH  2
#define NCHUNK  32
#define CHUNKLEN (SEQLEN / NCHUNK)   // 64

using f32x4 = __attribute__((ext_vector_type(4))) float;
using s16x8 = __attribute__((ext_vector_type(8))) short;

__device__ __forceinline__ float siluf(float x) {
  return x / (1.f + __expf(-x));
}
__device__ __forceinline__ float softplusf(float x) {
  return fmaxf(x, 0.f) + log1pf(__expf(-fabsf(x)));
}

// hi = truncate-to-bf16 (residual exact), lo = RNE-bf16(residual).
__device__ __forceinline__ void split_pair(float f0, float f1,
                                           unsigned& hw, unsigned& lw) {
  unsigned b0 = __float_as_uint(f0), b1 = __float_as_uint(f1);
  hw = (b0 >> 16) | (b1 & 0xFFFF0000u);
  float r0 = f0 - __uint_as_float(b0 & 0xFFFF0000u);
  float r1 = f1 - __uint_as_float(b1 & 0xFFFF0000u);
  unsigned c0 = __float_as_uint(r0); c0 += 0x7FFFu + ((c0 >> 16) & 1u);
  unsigned c1 = __float_as_uint(r1); c1 += 0x7FFFu + ((c1 >> 16) & 1u);
  lw = (c0 >> 16) | (c1 & 0xFFFF0000u);
}

// ---------------------------------------------------------------------------
// packsplit: in[R][K] fp32 row-major (k-major A operand) -> packed chunks
// out[chunk g = r*(K/32)+kc] = 128B: [16 uint hi words][16 uint lo words].
// One thread per 32-float chunk; fully coalesced 128B read + 128B write.
// ---------------------------------------------------------------------------
__global__ __launch_bounds__(256) void packsplit_k(
    const float* __restrict__ in, unsigned* __restrict__ out)
{
  size_t g = (size_t)blockIdx.x * 256 + threadIdx.x;
  float f[32];
#pragma unroll
  for (int q = 0; q < 8; ++q)
    *(float4*)&f[q * 4] = *(const float4*)(in + g * 32 + q * 4);
  unsigned* o = out + g * 32;
#pragma unroll
  for (int j = 0; j < 16; ++j) {
    unsigned hw, lw;
    split_pair(f[2 * j], f[2 * j + 1], hw, lw);
    o[j] = hw; o[16 + j] = lw;
  }
}

// ---------------------------------------------------------------------------
// transpack: in[K][N] fp32 row-major (weights) -> out packed [N][K/32][64],
// i.e. transpose + hi/lo split in one pass.  Block = 32 k x 256 n.
// ---------------------------------------------------------------------------
__global__ __launch_bounds__(256) void transpack_k(
    const float* __restrict__ in, unsigned* __restrict__ out, int K, int N)
{
  __shared__ float tile[32][257];
  const int tid = threadIdx.x;
  const int nb = blockIdx.x * 256;
  const int kc = blockIdx.y;
#pragma unroll 8
  for (int ky = 0; ky < 32; ++ky)
    tile[ky][tid] = in[(size_t)(kc * 32 + ky) * N + nb + tid];
  __syncthreads();
  unsigned* o = out + ((size_t)(nb + tid) * (K >> 5) + kc) * 32;
#pragma unroll
  for (int j = 0; j < 16; ++j) {
    unsigned hw, lw;
    split_pair(tile[2 * j][tid], tile[2 * j + 1][tid], hw, lw);
    o[j] = hw; o[16 + j] = lw;
  }
}

// ---------------------------------------------------------------------------
// Split-bf16 MFMA GEMM on packed operands.
// C[M,N] = A[M,K] @ Bt[N,K]^T; A,Bt packed as [row][K/32][32hi|32lo] bf16.
// 128x128 tile, BK=32, 4 waves (each 64x64 = 4x4 frags of 16x16x32).
// LDS tile: [128 rows][8 slots of 16B]; phys slot = un-slot ^ (row&7);
// un-slot 0..3 = hi k-groups, 4..7 = lo k-groups.  Staging source is
// pre-swizzled (rule 21); fragment reads are bank-minimum ds_read_b128.
// acc += ah*bh + ah*bl + al*bh  (ll term dropped, ~2^-16 rel).
// ---------------------------------------------------------------------------
__global__ __launch_bounds__(256, 2) void mgemm_split(
    const unsigned short* __restrict__ A, const unsigned short* __restrict__ Bt,
    float* __restrict__ C, int M, int N, int K, int ldc)
{
  __shared__ s16x8 AsV[128 * 8];   // 16 KB
  __shared__ s16x8 BsV[128 * 8];   // 16 KB

  const int tid = threadIdx.x;
  const int wv  = tid >> 6;
  const int ln  = tid & 63;
  const int wr  = wv >> 1, wc = wv & 1;
  const int m0  = blockIdx.y * 128, n0 = blockIdx.x * 128;
  const int K32 = K >> 5;

  const int rr = ln & 15;          // row/col within 16-frag
  const int ko = ln >> 4;          // k-group 0..3 (8 bf16 each)
  const int sh = ko ^ (rr & 7);          // phys slot of hi fragment
  const int sl = (4 | ko) ^ (rr & 7);    // phys slot of lo fragment

  // staging: instr i covers tile rows i*8..i*8+7; lane -> (row, phys slot)
  const int srow  = ln >> 3;             // row within 8-row group
  const int sslot = (ln & 7) ^ srow;     // pre-swizzled source (un-)slot

  f32x4 acc[4][4];
#pragma unroll
  for (int i = 0; i < 4; i++)
#pragma unroll
    for (int j = 0; j < 4; j++) acc[i][j] = (f32x4)0.f;

  for (int ktc = 0; ktc < K32; ++ktc) {
    __syncthreads();   // prior tile's reads done before overwrite
#pragma unroll
    for (int t = 0; t < 4; ++t) {
      int i = wv * 4 + t;
      const unsigned short* ga =
          A + ((size_t)(m0 + i * 8 + srow) * K32 + ktc) * 64 + sslot * 8;
      const unsigned short* gb =
          Bt + ((size_t)(n0 + i * 8 + srow) * K32 + ktc) * 64 + sslot * 8;
      __builtin_amdgcn_global_load_lds(
          (const __attribute__((address_space(1))) void*)ga,
          (__attribute__((address_space(3))) void*)((char*)AsV + i * 1024), 16, 0, 0);
      __builtin_amdgcn_global_load_lds(
          (const __attribute__((address_space(1))) void*)gb,
          (__attribute__((address_space(3))) void*)((char*)BsV + i * 1024), 16, 0, 0);
    }
    __syncthreads();   // vmcnt(0) drain before barrier (compiler-emitted)

    s16x8 ah[4], al[4], bh[4], bl[4];
#pragma unroll
    for (int mi = 0; mi < 4; ++mi) {
      int r = wr * 64 + mi * 16 + rr;
      ah[mi] = AsV[r * 8 + sh];
      al[mi] = AsV[r * 8 + sl];
    }
#pragma unroll
    for (int ni = 0; ni < 4; ++ni) {
      int c = wc * 64 + ni * 16 + rr;
      bh[ni] = BsV[c * 8 + sh];
      bl[ni] = BsV[c * 8 + sl];
    }
#pragma unroll
    for (int mi = 0; mi < 4; ++mi)
#pragma unroll
      for (int ni = 0; ni < 4; ++ni) {
        acc[mi][ni] = __builtin_amdgcn_mfma_f32_16x16x32_bf16(ah[mi], bh[ni], acc[mi][ni], 0, 0, 0);
        acc[mi][ni] = __builtin_amdgcn_mfma_f32_16x16x32_bf16(ah[mi], bl[ni], acc[mi][ni], 0, 0, 0);
        acc[mi][ni] = __builtin_amdgcn_mfma_f32_16x16x32_bf16(al[mi], bh[ni], acc[mi][ni], 0, 0, 0);
      }
  }

  // epilogue: D row = (ln>>4)*4 + i, col = ln&15  (m89-verified mapping)
  const int orow = (ln >> 4) * 4;
#pragma unroll
  for (int mi = 0; mi < 4; ++mi)
#pragma unroll
    for (int ni = 0; ni < 4; ++ni) {
      int rowg = m0 + wr * 64 + mi * 16 + orow;
      int colg = n0 + wc * 64 + ni * 16 + rr;
#pragma unroll
      for (int i = 0; i < 4; ++i)
        C[(size_t)(rowg + i) * ldc + colg] = acc[mi][ni][i];
    }
}

// ---------------------------------------------------------------------------
// fp32 GEMM (kept for the small K=64 dt projection), 128x128x16 tiles.
// EPI==1: C = softplus(acc + bias[col]).
// ---------------------------------------------------------------------------
template <int EPI>
__global__ __launch_bounds__(256, 2) void sgemm_k(
    const float* __restrict__ A, const float* __restrict__ B,
    const float* __restrict__ bias, float* __restrict__ C,
    int M, int N, int K, int lda, int ldb, int ldc)
{
  __shared__ float As[16][132];
  __shared__ float Bs[16][128];

  const int tid = threadIdx.x;
  const int m0 = blockIdx.y * 128;
  const int n0 = blockIdx.x * 128;
  const int tx = tid & 15;
  const int ty = tid >> 4;

  float acc[2][2][4][4];
#pragma unroll
  for (int a = 0; a < 2; a++)
#pragma unroll
    for (int b2 = 0; b2 < 2; b2++)
#pragma unroll
      for (int i = 0; i < 4; i++)
#pragma unroll
        for (int j = 0; j < 4; j++) acc[a][b2][i][j] = 0.f;

  for (int k0 = 0; k0 < K; k0 += 16) {
#pragma unroll
    for (int t = 0; t < 2; ++t) {
      int i = tid + t * 256;
      int row = i >> 2;
      int kq = (i & 3) * 4;
      float4 v = *(const float4*)(A + (size_t)(m0 + row) * lda + k0 + kq);
      As[kq + 0][row] = v.x; As[kq + 1][row] = v.y;
      As[kq + 2][row] = v.z; As[kq + 3][row] = v.w;
    }
#pragma unroll
    for (int t = 0; t < 2; ++t) {
      int i = tid + t * 256;
      int kr = i >> 5;
      int cq = (i & 31) * 4;
      *(float4*)&Bs[kr][cq] = *(const float4*)(B + (size_t)(k0 + kr) * ldb + n0 + cq);
    }
    __syncthreads();
#pragma unroll
    for (int kk = 0; kk < 16; ++kk) {
      float4 a0 = *(const float4*)&As[kk][ty * 4];
      float4 a1 = *(const float4*)&As[kk][64 + ty * 4];
      float4 b0 = *(const float4*)&Bs[kk][tx * 4];
      float4 b1 = *(const float4*)&Bs[kk][64 + tx * 4];
      float av[2][4] = {{a0.x, a0.y, a0.z, a0.w}, {a1.x, a1.y, a1.z, a1.w}};
      float bv[2][4] = {{b0.x, b0.y, b0.z, b0.w}, {b1.x, b1.y, b1.z, b1.w}};
#pragma unroll
      for (int a = 0; a < 2; a++)
#pragma unroll
        for (int i = 0; i < 4; i++)
#pragma unroll
          for (int b2 = 0; b2 < 2; b2++)
#pragma unroll
            for (int j = 0; j < 4; j++)
              acc[a][b2][i][j] = fmaf(av[a][i], bv[b2][j], acc[a][b2][i][j]);
    }
    __syncthreads();
  }

#pragma unroll
  for (int a = 0; a < 2; a++) {
#pragma unroll
    for (int i = 0; i < 4; i++) {
      int row = m0 + a * 64 + ty * 4 + i;
#pragma unroll
      for (int b2 = 0; b2 < 2; b2++) {
        int col = n0 + b2 * 64 + tx * 4;
        float4 v = make_float4(acc[a][b2][i][0], acc[a][b2][i][1],
                               acc[a][b2][i][2], acc[a][b2][i][3]);
        if (EPI == 1) {
          v.x = softplusf(v.x + bias[col + 0]);
          v.y = softplusf(v.y + bias[col + 1]);
          v.z = softplusf(v.z + bias[col + 2]);
          v.w = softplusf(v.w + bias[col + 3]);
        }
        *(float4*)(C + (size_t)row * ldc + col) = v;
      }
    }
  }
}

// ---------------------------------------------------------------------------
// depthwise causal conv1d (taps=4) + bias + silu
// ---------------------------------------------------------------------------
__global__ __launch_bounds__(256) void conv_silu_k(
    const float* __restrict__ xz, const float* __restrict__ cw,
    const float* __restrict__ cb, float* __restrict__ xi)
{
  int idx = blockIdx.x * 256 + threadIdx.x;
  int d = idx & (D_INNER - 1);
  int row = idx >> 11;
  int l = row & (SEQLEN - 1);
  float4 w = *(const float4*)(cw + d * 4);
  const float wv[4] = {w.x, w.y, w.z, w.w};
  float acc = cb[d];
#pragma unroll
  for (int j = 0; j < 4; j++) {
    int ll = l - 3 + j;
    if (ll >= 0)
      acc = fmaf(wv[j], xz[(size_t)(row - 3 + j) * 4096 + d], acc);
  }
  xi[idx] = siluf(acc);
}

// ---------------------------------------------------------------------------
// x_dbl = xi(4096x2048) @ W_x(2048x96), split-K + atomics.
// ---------------------------------------------------------------------------
__global__ __launch_bounds__(256) void xdbl_k(
    const float* __restrict__ xi, const float* __restrict__ Wx,
    float* __restrict__ xdbl)
{
  __shared__ float Xs[32][66];
  __shared__ float Ws[32][96];

  const int tid = threadIdx.x;
  const int r0 = blockIdx.x * 64;
  const int k0 = blockIdx.y * 256;
  const int rowg = tid >> 3;
  const int colg = tid & 7;

  float acc[2][12];
#pragma unroll
  for (int i = 0; i < 2; i++)
#pragma unroll
    for (int j = 0; j < 12; j++) acc[i][j] = 0.f;

  for (int kc = 0; kc < 256; kc += 32) {
    int kbase = k0 + kc;
#pragma unroll
    for (int t = 0; t < 2; t++) {
      int i = tid + t * 256;
      int row = i >> 3;
      int kq = (i & 7) * 4;
      float4 v = *(const float4*)(xi + (size_t)(r0 + row) * 2048 + kbase + kq);
      Xs[kq + 0][row] = v.x; Xs[kq + 1][row] = v.y;
      Xs[kq + 2][row] = v.z; Xs[kq + 3][row] = v.w;
    }
#pragma unroll
    for (int t = 0; t < 3; t++) {
      int i = tid + t * 256;
      int kr = i / 24;
      int cq = (i % 24) * 4;
      *(float4*)&Ws[kr][cq] = *(const float4*)(Wx + (size_t)(kbase + kr) * 96 + cq);
    }
    __syncthreads();
#pragma unroll
    for (int kk = 0; kk < 32; kk++) {
      float2 a = *(const float2*)&Xs[kk][rowg * 2];
      float4 b0 = *(const float4*)&Ws[kk][colg * 12];
      float4 b1 = *(const float4*)&Ws[kk][colg * 12 + 4];
      float4 b2 = *(const float4*)&Ws[kk][colg * 12 + 8];
      float bv[12] = {b0.x, b0.y, b0.z, b0.w, b1.x, b1.y, b1.z, b1.w,
                      b2.x, b2.y, b2.z, b2.w};
#pragma unroll
      for (int j = 0; j < 12; j++) {
        acc[0][j] = fmaf(a.x, bv[j], acc[0][j]);
        acc[1][j] = fmaf(a.y, bv[j], acc[1][j]);
      }
    }
    __syncthreads();
  }
#pragma unroll
  for (int i = 0; i < 2; i++) {
    int row = r0 + rowg * 2 + i;
#pragma unroll
    for (int j = 0; j < 12; j++)
      atomicAdd(&xdbl[(size_t)row * 96 + colg * 12 + j], acc[i][j]);
  }
}

__global__ __launch_bounds__(256) void aprep_k(const float* __restrict__ A_log,
                                               float* __restrict__ A2)
{
  int i = blockIdx.x * 256 + threadIdx.x;
  A2[i] = -__expf(A_log[i]);
}

// ---------------------------------------------------------------------------
// chunked selective scan (3 passes) — unchanged
// ---------------------------------------------------------------------------
__global__ __launch_bounds__(256) void scan_pass1(
    const float* __restrict__ dt, const float* __restrict__ xi,
    const float* __restrict__ xdbl, const float* __restrict__ A2,
    float* __restrict__ cP, float* __restrict__ cH)
{
  int d = blockIdx.x * 256 + threadIdx.x;
  int c = blockIdx.y;
  int b = blockIdx.z;
  float a2[D_STATE], h[D_STATE], P[D_STATE];
#pragma unroll
  for (int n = 0; n < D_STATE; n++) {
    a2[n] = A2[d * D_STATE + n];
    h[n] = 0.f;
    P[n] = 1.f;
  }
  int rowbase = b * SEQLEN + c * CHUNKLEN;
  for (int l = 0; l < CHUNKLEN; l++) {
    int row = rowbase + l;
    float dtv = dt[(size_t)row * D_INNER + d];
    float xv = xi[(size_t)row * D_INNER + d];
    float dtx = dtv * xv;
    const float* Bp = xdbl + (size_t)row * 96 + 64;
#pragma unroll
    for (int n = 0; n < D_STATE; n++) {
      float dA = __expf(dtv * a2[n]);
      P[n] *= dA;
      h[n] = fmaf(dA, h[n], dtx * Bp[n]);
    }
  }
  size_t base = ((size_t)(b * D_INNER + d) * NCHUNK + c) * D_STATE;
#pragma unroll
  for (int n = 0; n < D_STATE; n++) {
    cP[base + n] = P[n];
    cH[base + n] = h[n];
  }
}

__global__ __launch_bounds__(256) void scan_pass2(
    const float* __restrict__ cP, float* __restrict__ cH)
{
  int t = blockIdx.x * 256 + threadIdx.x;
  size_t base = (size_t)(t >> 4) * (NCHUNK * D_STATE) + (t & 15);
  float h = 0.f;
  for (int c = 0; c < NCHUNK; c++) {
    size_t idx = base + (size_t)c * D_STATE;
    float Pv = cP[idx];
    float q = cH[idx];
    cH[idx] = h;
    h = fmaf(Pv, h, q);
  }
}

__global__ __launch_bounds__(256) void scan_pass3(
    float* __restrict__ dtyg, const float* __restrict__ xi,
    const float* __restrict__ xdbl, const float* __restrict__ A2,
    const float* __restrict__ cH, const float* __restrict__ Dvec,
    const float* __restrict__ xz)
{
  int d = blockIdx.x * 256 + threadIdx.x;
  int c = blockIdx.y;
  int b = blockIdx.z;
  float a2[D_STATE], h[D_STATE];
  size_t base = ((size_t)(b * D_INNER + d) * NCHUNK + c) * D_STATE;
#pragma unroll
  for (int n = 0; n < D_STATE; n++) {
    a2[n] = A2[d * D_STATE + n];
    h[n] = cH[base + n];
  }
  float Dd = Dvec[d];
  int rowbase = b * SEQLEN + c * CHUNKLEN;
  for (int l = 0; l < CHUNKLEN; l++) {
    int row = rowbase + l;
    float dtv = dtyg[(size_t)row * D_INNER + d];
    float xv = xi[(size_t)row * D_INNER + d];
    float dtx = dtv * xv;
    const float* Bp = xdbl + (size_t)row * 96 + 64;
    const float* Cp = Bp + D_STATE;
    float y = Dd * xv;
#pragma unroll
    for (int n = 0; n < D_STATE; n++) {
      float dA = __expf(dtv * a2[n]);
      h[n] = fmaf(dA, h[n], dtx * Bp[n]);
      y = fmaf(h[n], Cp[n], y);
    }
    float z = xz[(size_t)row * 4096 + D_INNER + d];
    dtyg[(size_t)row * D_INNER + d] = y * siluf(z);
  }
}

// ---------------------------------------------------------------------------
extern "C" void kernel_launch(void* const* d_in, const int* in_sizes, int n_in,
                              void* d_out, int out_size, void* d_ws,
                              size_t ws_size, hipStream_t stream)
{
  const float* x     = (const float*)d_in[0];
  const float* W_in  = (const float*)d_in[1];
  const float* cw    = (const float*)d_in[2];
  const float* cb    = (const float*)d_in[3];
  const float* W_x   = (const float*)d_in[4];
  const float* W_dt  = (const float*)d_in[5];
  const float* b_dt  = (const float*)d_in[6];
  const float* A_log = (const float*)d_in[7];
  const float* Dv    = (const float*)d_in[8];
  const float* W_out = (const float*)d_in[9];
  float* out = (float*)d_out;

  float* ws    = (float*)d_ws;
  float* xz    = ws;                       // 16,777,216
  float* xi    = xz + 16777216;            //  8,388,608
  float* xdbl  = xi + 8388608;             //    393,216
  float* dtyg  = xdbl + 393216;            //  8,388,608
  float* A2    = dtyg + 8388608;           //     32,768
  float* cP    = A2 + 32768;               //  2,097,152
  float* cH    = cP + 2097152;             //  2,097,152

  // packed hi/lo bf16 overlays (each chunk = 128B = 32hi|32lo bf16)
  unsigned* WinTP  = (unsigned*)dtyg;                 // 16 MB (dtyg[0:4M])
  unsigned* xP     = (unsigned*)(dtyg + 4194304);     // 16 MB (dtyg[4M:8M])
  unsigned* ygP    = (unsigned*)xi;                   // 32 MB (xi dead post-scan)
  unsigned* WoutTP = (unsigned*)cP;                   //  8 MB (cP dead post-pass2)

  hipMemsetAsync(xdbl, 0, 393216 * sizeof(float), stream);
  aprep_k<<<128, 256, 0, stream>>>(A_log, A2);

  // W_in (1024x4096) -> transposed+packed WinTP [4096][32][64]
  transpack_k<<<dim3(16, 32), 256, 0, stream>>>(W_in, WinTP, 1024, 4096);
  // x (4096x1024) -> packed xP
  packsplit_k<<<512, 256, 0, stream>>>(x, xP);

  // xz = x @ W_in   (4096x4096, K=1024) via packed split-bf16 MFMA
  mgemm_split<<<dim3(32, 32), 256, 0, stream>>>(
      (const unsigned short*)xP, (const unsigned short*)WinTP, xz,
      4096, 4096, 1024, 4096);

  conv_silu_k<<<32768, 256, 0, stream>>>(xz, cw, cb, xi);

  xdbl_k<<<dim3(64, 8), 256, 0, stream>>>(xi, W_x, xdbl);

  // dt = softplus(x_dbl[:, :64] @ W_dt + b_dt)  (K=64, stays fp32)
  // overwrites WinTP/xP region — both dead after GEMM1.
  sgemm_k<1><<<dim3(16, 32), 256, 0, stream>>>(xdbl, W_dt, b_dt, dtyg,
                                               4096, 2048, 64, 96, 2048, 2048);

  scan_pass1<<<dim3(8, NCHUNK, NBATCH), 256, 0, stream>>>(dtyg, xi, xdbl, A2, cP, cH);
  scan_pass2<<<256, 256, 0, stream>>>(cP, cH);
  scan_pass3<<<dim3(8, NCHUNK, NBATCH), 256, 0, stream>>>(dtyg, xi, xdbl, A2, cH, Dv, xz);

  // yg (4096x2048, in dtyg) -> packed ygP (over xi; xi dead after pass3)
  packsplit_k<<<1024, 256, 0, stream>>>(dtyg, ygP);
  // W_out (2048x1024) -> transposed+packed WoutTP [1024][64][64]
  transpack_k<<<dim3(4, 64), 256, 0, stream>>>(W_out, WoutTP, 2048, 1024);

  // out = yg @ W_out  (4096x1024, K=2048) via packed split-bf16 MFMA
  mgemm_split<<<dim3(8, 32), 256, 0, stream>>>(
      (const unsigned short*)ygP, (const unsigned short*)WoutTP, out,
      4096, 1024, 2048, 1024);
}

// Round 6
// 478.831 us; speedup vs baseline: 2.2685x; 1.3030x over previous
//
#include <hip/hip_runtime.h>
#include <math.h>

// ---------------------------------------------------------------------------
// SelectiveSSM (Mamba block) for MI355X — round 5 (resubmit): xdbl projection
// moved from atomic split-K VALU GEMM (180 µs of pure stall) to the packed
// split-bf16 MFMA GEMM with private per-slice partials + reduce (no atomics).
//
// ws layout (floats):
//   xz    : 16,777,216   (xi_raw 0..2047 | z 2048..4095)
//   xi    :  8,388,608   (post conv+silu; reused as ygP after pass3)
//   xdbl  :    393,216   (WxTP first, then dt_lin 0..63 | B 64..79 | C 80..95)
//   dtyg  :  8,388,608   (WinTP+xP -> xiP -> dt -> yg)
//   A2    :     32,768
//   cP    :  2,097,152   (xdbl partials [8][4096][96] span cP+cH; then scan
//   cH    :  2,097,152    chunk-products; cP reused as WoutTP after pass2)
// total ≈ 152.7 MB (same as verified round-0 layout)
// ---------------------------------------------------------------------------

#define D_INNER 2048
#define D_STATE 16
#define SEQLEN  2048
#define NBATCH  2
#define NCHUNK  32
#define CHUNKLEN (SEQLEN / NCHUNK)   // 64

using f32x4 = __attribute__((ext_vector_type(4))) float;
using s16x8 = __attribute__((ext_vector_type(8))) short;

__device__ __forceinline__ float siluf(float x) {
  return x / (1.f + __expf(-x));
}
__device__ __forceinline__ float softplusf(float x) {
  return fmaxf(x, 0.f) + log1pf(__expf(-fabsf(x)));
}

// hi = truncate-to-bf16 (residual exact), lo = RNE-bf16(residual).
__device__ __forceinline__ void split_pair(float f0, float f1,
                                           unsigned& hw, unsigned& lw) {
  unsigned b0 = __float_as_uint(f0), b1 = __float_as_uint(f1);
  hw = (b0 >> 16) | (b1 & 0xFFFF0000u);
  float r0 = f0 - __uint_as_float(b0 & 0xFFFF0000u);
  float r1 = f1 - __uint_as_float(b1 & 0xFFFF0000u);
  unsigned c0 = __float_as_uint(r0); c0 += 0x7FFFu + ((c0 >> 16) & 1u);
  unsigned c1 = __float_as_uint(r1); c1 += 0x7FFFu + ((c1 >> 16) & 1u);
  lw = (c0 >> 16) | (c1 & 0xFFFF0000u);
}

// ---------------------------------------------------------------------------
// packsplit: in[R][K] fp32 row-major (k-major A operand) -> packed chunks
// out[chunk g = r*(K/32)+kc] = 128B: [16 uint hi words][16 uint lo words].
// ---------------------------------------------------------------------------
__global__ __launch_bounds__(256) void packsplit_k(
    const float* __restrict__ in, unsigned* __restrict__ out)
{
  size_t g = (size_t)blockIdx.x * 256 + threadIdx.x;
  float f[32];
#pragma unroll
  for (int q = 0; q < 8; ++q)
    *(float4*)&f[q * 4] = *(const float4*)(in + g * 32 + q * 4);
  unsigned* o = out + g * 32;
#pragma unroll
  for (int j = 0; j < 16; ++j) {
    unsigned hw, lw;
    split_pair(f[2 * j], f[2 * j + 1], hw, lw);
    o[j] = hw; o[16 + j] = lw;
  }
}

// ---------------------------------------------------------------------------
// transpack: in[K][N] fp32 row-major (weights) -> out packed [N][K/32][64].
// ---------------------------------------------------------------------------
__global__ __launch_bounds__(256) void transpack_k(
    const float* __restrict__ in, unsigned* __restrict__ out, int K, int N)
{
  __shared__ float tile[32][257];
  const int tid = threadIdx.x;
  const int nb = blockIdx.x * 256;
  const int kc = blockIdx.y;
#pragma unroll 8
  for (int ky = 0; ky < 32; ++ky)
    tile[ky][tid] = in[(size_t)(kc * 32 + ky) * N + nb + tid];
  __syncthreads();
  unsigned* o = out + ((size_t)(nb + tid) * (K >> 5) + kc) * 32;
#pragma unroll
  for (int j = 0; j < 16; ++j) {
    unsigned hw, lw;
    split_pair(tile[2 * j][tid], tile[2 * j + 1][tid], hw, lw);
    o[j] = hw; o[16 + j] = lw;
  }
}

// ---------------------------------------------------------------------------
// transpack for W_x: in[2048][96] -> out packed [128][64][64], rows 96..127
// zero-padded.  grid = 64 kc-blocks, 128 threads (one per output row n).
// ---------------------------------------------------------------------------
__global__ __launch_bounds__(128) void transpack_wx_k(
    const float* __restrict__ Wx, unsigned* __restrict__ out)
{
  const int n = threadIdx.x;     // 0..127
  const int kc = blockIdx.x;     // 0..63
  float f[32];
#pragma unroll
  for (int j = 0; j < 32; ++j)
    f[j] = (n < 96) ? Wx[(size_t)(kc * 32 + j) * 96 + n] : 0.f;
  unsigned* o = out + ((size_t)n * 64 + kc) * 32;
#pragma unroll
  for (int j = 0; j < 16; ++j) {
    unsigned hw, lw;
    split_pair(f[2 * j], f[2 * j + 1], hw, lw);
    o[j] = hw; o[16 + j] = lw;
  }
}

// ---------------------------------------------------------------------------
// Split-bf16 MFMA GEMM on packed operands.
// C[M,N] = A[M,K] @ Bt[N,K]^T; A,Bt packed as [row][K/32][32hi|32lo] bf16.
// 128x128 tile, BK=32, 4 waves.  LDS phys slot = un-slot ^ (row&7); staging
// source pre-swizzled (rule 21); reads are bank-minimum ds_read_b128.
// acc += ah*bh + ah*bl + al*bh.
// ---------------------------------------------------------------------------
__global__ __launch_bounds__(256, 2) void mgemm_split(
    const unsigned short* __restrict__ A, const unsigned short* __restrict__ Bt,
    float* __restrict__ C, int M, int N, int K, int ldc)
{
  __shared__ s16x8 AsV[128 * 8];   // 16 KB
  __shared__ s16x8 BsV[128 * 8];   // 16 KB

  const int tid = threadIdx.x;
  const int wv  = tid >> 6;
  const int ln  = tid & 63;
  const int wr  = wv >> 1, wc = wv & 1;
  const int m0  = blockIdx.y * 128, n0 = blockIdx.x * 128;
  const int K32 = K >> 5;

  const int rr = ln & 15;
  const int ko = ln >> 4;
  const int sh = ko ^ (rr & 7);
  const int sl = (4 | ko) ^ (rr & 7);

  const int srow  = ln >> 3;
  const int sslot = (ln & 7) ^ srow;

  f32x4 acc[4][4];
#pragma unroll
  for (int i = 0; i < 4; i++)
#pragma unroll
    for (int j = 0; j < 4; j++) acc[i][j] = (f32x4)0.f;

  for (int ktc = 0; ktc < K32; ++ktc) {
    __syncthreads();
#pragma unroll
    for (int t = 0; t < 4; ++t) {
      int i = wv * 4 + t;
      const unsigned short* ga =
          A + ((size_t)(m0 + i * 8 + srow) * K32 + ktc) * 64 + sslot * 8;
      const unsigned short* gb =
          Bt + ((size_t)(n0 + i * 8 + srow) * K32 + ktc) * 64 + sslot * 8;
      __builtin_amdgcn_global_load_lds(
          (const __attribute__((address_space(1))) void*)ga,
          (__attribute__((address_space(3))) void*)((char*)AsV + i * 1024), 16, 0, 0);
      __builtin_amdgcn_global_load_lds(
          (const __attribute__((address_space(1))) void*)gb,
          (__attribute__((address_space(3))) void*)((char*)BsV + i * 1024), 16, 0, 0);
    }
    __syncthreads();

    s16x8 ah[4], al[4], bh[4], bl[4];
#pragma unroll
    for (int mi = 0; mi < 4; ++mi) {
      int r = wr * 64 + mi * 16 + rr;
      ah[mi] = AsV[r * 8 + sh];
      al[mi] = AsV[r * 8 + sl];
    }
#pragma unroll
    for (int ni = 0; ni < 4; ++ni) {
      int c = wc * 64 + ni * 16 + rr;
      bh[ni] = BsV[c * 8 + sh];
      bl[ni] = BsV[c * 8 + sl];
    }
#pragma unroll
    for (int mi = 0; mi < 4; ++mi)
#pragma unroll
      for (int ni = 0; ni < 4; ++ni) {
        acc[mi][ni] = __builtin_amdgcn_mfma_f32_16x16x32_bf16(ah[mi], bh[ni], acc[mi][ni], 0, 0, 0);
        acc[mi][ni] = __builtin_amdgcn_mfma_f32_16x16x32_bf16(ah[mi], bl[ni], acc[mi][ni], 0, 0, 0);
        acc[mi][ni] = __builtin_amdgcn_mfma_f32_16x16x32_bf16(al[mi], bh[ni], acc[mi][ni], 0, 0, 0);
      }
  }

  const int orow = (ln >> 4) * 4;
#pragma unroll
  for (int mi = 0; mi < 4; ++mi)
#pragma unroll
    for (int ni = 0; ni < 4; ++ni) {
      int rowg = m0 + wr * 64 + mi * 16 + orow;
      int colg = n0 + wc * 64 + ni * 16 + rr;
#pragma unroll
      for (int i = 0; i < 4; ++i)
        C[(size_t)(rowg + i) * ldc + colg] = acc[mi][ni][i];
    }
}

// ---------------------------------------------------------------------------
// xdbl split-K MFMA: P[kz][4096][96] partials, kz = blockIdx.x (8 slices of
// K=256), m-tile = blockIdx.y.  Single 128-col tile; cols >= 96 discarded.
// A = xiP [4096][64][64] packed, Bt = WxTP [128][64][64] packed (zero-padded).
// ---------------------------------------------------------------------------
__global__ __launch_bounds__(256, 2) void xdbl_mfma_k(
    const unsigned short* __restrict__ A, const unsigned short* __restrict__ Bt,
    float* __restrict__ P)
{
  __shared__ s16x8 AsV[128 * 8];
  __shared__ s16x8 BsV[128 * 8];

  const int tid = threadIdx.x;
  const int wv  = tid >> 6;
  const int ln  = tid & 63;
  const int wr  = wv >> 1, wc = wv & 1;
  const int kz  = blockIdx.x;            // 0..7
  const int m0  = blockIdx.y * 128;
  const int K32 = 64;                    // K=2048

  const int rr = ln & 15;
  const int ko = ln >> 4;
  const int sh = ko ^ (rr & 7);
  const int sl = (4 | ko) ^ (rr & 7);
  const int srow  = ln >> 3;
  const int sslot = (ln & 7) ^ srow;

  f32x4 acc[4][4];
#pragma unroll
  for (int i = 0; i < 4; i++)
#pragma unroll
    for (int j = 0; j < 4; j++) acc[i][j] = (f32x4)0.f;

  for (int ktc = kz * 8; ktc < kz * 8 + 8; ++ktc) {
    __syncthreads();
#pragma unroll
    for (int t = 0; t < 4; ++t) {
      int i = wv * 4 + t;
      const unsigned short* ga =
          A + ((size_t)(m0 + i * 8 + srow) * K32 + ktc) * 64 + sslot * 8;
      const unsigned short* gb =
          Bt + ((size_t)(i * 8 + srow) * K32 + ktc) * 64 + sslot * 8;
      __builtin_amdgcn_global_load_lds(
          (const __attribute__((address_space(1))) void*)ga,
          (__attribute__((address_space(3))) void*)((char*)AsV + i * 1024), 16, 0, 0);
      __builtin_amdgcn_global_load_lds(
          (const __attribute__((address_space(1))) void*)gb,
          (__attribute__((address_space(3))) void*)((char*)BsV + i * 1024), 16, 0, 0);
    }
    __syncthreads();

    s16x8 ah[4], al[4], bh[4], bl[4];
#pragma unroll
    for (int mi = 0; mi < 4; ++mi) {
      int r = wr * 64 + mi * 16 + rr;
      ah[mi] = AsV[r * 8 + sh];
      al[mi] = AsV[r * 8 + sl];
    }
#pragma unroll
    for (int ni = 0; ni < 4; ++ni) {
      int c = wc * 64 + ni * 16 + rr;
      bh[ni] = BsV[c * 8 + sh];
      bl[ni] = BsV[c * 8 + sl];
    }
#pragma unroll
    for (int mi = 0; mi < 4; ++mi)
#pragma unroll
      for (int ni = 0; ni < 4; ++ni) {
        acc[mi][ni] = __builtin_amdgcn_mfma_f32_16x16x32_bf16(ah[mi], bh[ni], acc[mi][ni], 0, 0, 0);
        acc[mi][ni] = __builtin_amdgcn_mfma_f32_16x16x32_bf16(ah[mi], bl[ni], acc[mi][ni], 0, 0, 0);
        acc[mi][ni] = __builtin_amdgcn_mfma_f32_16x16x32_bf16(al[mi], bh[ni], acc[mi][ni], 0, 0, 0);
      }
  }

  const int orow = (ln >> 4) * 4;
#pragma unroll
  for (int mi = 0; mi < 4; ++mi)
#pragma unroll
    for (int ni = 0; ni < 4; ++ni) {
      int rowg = m0 + wr * 64 + mi * 16 + orow;
      int colg = wc * 64 + ni * 16 + rr;
      if (colg < 96) {
#pragma unroll
        for (int i = 0; i < 4; ++i)
          P[((size_t)kz * 4096 + rowg + i) * 96 + colg] = acc[mi][ni][i];
      }
    }
}

// xdbl[i] = sum over 8 partial slices
__global__ __launch_bounds__(256) void xdbl_reduce_k(
    const float* __restrict__ P, float* __restrict__ xdbl)
{
  int i = blockIdx.x * 256 + threadIdx.x;   // 0..393215
  float s = 0.f;
#pragma unroll
  for (int kz = 0; kz < 8; ++kz) s += P[(size_t)kz * 393216 + i];
  xdbl[i] = s;
}

// ---------------------------------------------------------------------------
// fp32 GEMM (small K=64 dt projection), EPI==1: softplus(acc + bias[col]).
// ---------------------------------------------------------------------------
template <int EPI>
__global__ __launch_bounds__(256, 2) void sgemm_k(
    const float* __restrict__ A, const float* __restrict__ B,
    const float* __restrict__ bias, float* __restrict__ C,
    int M, int N, int K, int lda, int ldb, int ldc)
{
  __shared__ float As[16][132];
  __shared__ float Bs[16][128];

  const int tid = threadIdx.x;
  const int m0 = blockIdx.y * 128;
  const int n0 = blockIdx.x * 128;
  const int tx = tid & 15;
  const int ty = tid >> 4;

  float acc[2][2][4][4];
#pragma unroll
  for (int a = 0; a < 2; a++)
#pragma unroll
    for (int b2 = 0; b2 < 2; b2++)
#pragma unroll
      for (int i = 0; i < 4; i++)
#pragma unroll
        for (int j = 0; j < 4; j++) acc[a][b2][i][j] = 0.f;

  for (int k0 = 0; k0 < K; k0 += 16) {
#pragma unroll
    for (int t = 0; t < 2; ++t) {
      int i = tid + t * 256;
      int row = i >> 2;
      int kq = (i & 3) * 4;
      float4 v = *(const float4*)(A + (size_t)(m0 + row) * lda + k0 + kq);
      As[kq + 0][row] = v.x; As[kq + 1][row] = v.y;
      As[kq + 2][row] = v.z; As[kq + 3][row] = v.w;
    }
#pragma unroll
    for (int t = 0; t < 2; ++t) {
      int i = tid + t * 256;
      int kr = i >> 5;
      int cq = (i & 31) * 4;
      *(float4*)&Bs[kr][cq] = *(const float4*)(B + (size_t)(k0 + kr) * ldb + n0 + cq);
    }
    __syncthreads();
#pragma unroll
    for (int kk = 0; kk < 16; ++kk) {
      float4 a0 = *(const float4*)&As[kk][ty * 4];
      float4 a1 = *(const float4*)&As[kk][64 + ty * 4];
      float4 b0 = *(const float4*)&Bs[kk][tx * 4];
      float4 b1 = *(const float4*)&Bs[kk][64 + tx * 4];
      float av[2][4] = {{a0.x, a0.y, a0.z, a0.w}, {a1.x, a1.y, a1.z, a1.w}};
      float bv[2][4] = {{b0.x, b0.y, b0.z, b0.w}, {b1.x, b1.y, b1.z, b1.w}};
#pragma unroll
      for (int a = 0; a < 2; a++)
#pragma unroll
        for (int i = 0; i < 4; i++)
#pragma unroll
          for (int b2 = 0; b2 < 2; b2++)
#pragma unroll
            for (int j = 0; j < 4; j++)
              acc[a][b2][i][j] = fmaf(av[a][i], bv[b2][j], acc[a][b2][i][j]);
    }
    __syncthreads();
  }

#pragma unroll
  for (int a = 0; a < 2; a++) {
#pragma unroll
    for (int i = 0; i < 4; i++) {
      int row = m0 + a * 64 + ty * 4 + i;
#pragma unroll
      for (int b2 = 0; b2 < 2; b2++) {
        int col = n0 + b2 * 64 + tx * 4;
        float4 v = make_float4(acc[a][b2][i][0], acc[a][b2][i][1],
                               acc[a][b2][i][2], acc[a][b2][i][3]);
        if (EPI == 1) {
          v.x = softplusf(v.x + bias[col + 0]);
          v.y = softplusf(v.y + bias[col + 1]);
          v.z = softplusf(v.z + bias[col + 2]);
          v.w = softplusf(v.w + bias[col + 3]);
        }
        *(float4*)(C + (size_t)row * ldc + col) = v;
      }
    }
  }
}

// ---------------------------------------------------------------------------
// depthwise causal conv1d (taps=4) + bias + silu
// ---------------------------------------------------------------------------
__global__ __launch_bounds__(256) void conv_silu_k(
    const float* __restrict__ xz, const float* __restrict__ cw,
    const float* __restrict__ cb, float* __restrict__ xi)
{
  int idx = blockIdx.x * 256 + threadIdx.x;
  int d = idx & (D_INNER - 1);
  int row = idx >> 11;
  int l = row & (SEQLEN - 1);
  float4 w = *(const float4*)(cw + d * 4);
  const float wv[4] = {w.x, w.y, w.z, w.w};
  float acc = cb[d];
#pragma unroll
  for (int j = 0; j < 4; j++) {
    int ll = l - 3 + j;
    if (ll >= 0)
      acc = fmaf(wv[j], xz[(size_t)(row - 3 + j) * 4096 + d], acc);
  }
  xi[idx] = siluf(acc);
}

__global__ __launch_bounds__(256) void aprep_k(const float* __restrict__ A_log,
                                               float* __restrict__ A2)
{
  int i = blockIdx.x * 256 + threadIdx.x;
  A2[i] = -__expf(A_log[i]);
}

// ---------------------------------------------------------------------------
// chunked selective scan (3 passes) — unchanged
// ---------------------------------------------------------------------------
__global__ __launch_bounds__(256) void scan_pass1(
    const float* __restrict__ dt, const float* __restrict__ xi,
    const float* __restrict__ xdbl, const float* __restrict__ A2,
    float* __restrict__ cP, float* __restrict__ cH)
{
  int d = blockIdx.x * 256 + threadIdx.x;
  int c = blockIdx.y;
  int b = blockIdx.z;
  float a2[D_STATE], h[D_STATE], P[D_STATE];
#pragma unroll
  for (int n = 0; n < D_STATE; n++) {
    a2[n] = A2[d * D_STATE + n];
    h[n] = 0.f;
    P[n] = 1.f;
  }
  int rowbase = b * SEQLEN + c * CHUNKLEN;
  for (int l = 0; l < CHUNKLEN; l++) {
    int row = rowbase + l;
    float dtv = dt[(size_t)row * D_INNER + d];
    float xv = xi[(size_t)row * D_INNER + d];
    float dtx = dtv * xv;
    const float* Bp = xdbl + (size_t)row * 96 + 64;
#pragma unroll
    for (int n = 0; n < D_STATE; n++) {
      float dA = __expf(dtv * a2[n]);
      P[n] *= dA;
      h[n] = fmaf(dA, h[n], dtx * Bp[n]);
    }
  }
  size_t base = ((size_t)(b * D_INNER + d) * NCHUNK + c) * D_STATE;
#pragma unroll
  for (int n = 0; n < D_STATE; n++) {
    cP[base + n] = P[n];
    cH[base + n] = h[n];
  }
}

__global__ __launch_bounds__(256) void scan_pass2(
    const float* __restrict__ cP, float* __restrict__ cH)
{
  int t = blockIdx.x * 256 + threadIdx.x;
  size_t base = (size_t)(t >> 4) * (NCHUNK * D_STATE) + (t & 15);
  float h = 0.f;
  for (int c = 0; c < NCHUNK; c++) {
    size_t idx = base + (size_t)c * D_STATE;
    float Pv = cP[idx];
    float q = cH[idx];
    cH[idx] = h;
    h = fmaf(Pv, h, q);
  }
}

__global__ __launch_bounds__(256) void scan_pass3(
    float* __restrict__ dtyg, const float* __restrict__ xi,
    const float* __restrict__ xdbl, const float* __restrict__ A2,
    const float* __restrict__ cH, const float* __restrict__ Dvec,
    const float* __restrict__ xz)
{
  int d = blockIdx.x * 256 + threadIdx.x;
  int c = blockIdx.y;
  int b = blockIdx.z;
  float a2[D_STATE], h[D_STATE];
  size_t base = ((size_t)(b * D_INNER + d) * NCHUNK + c) * D_STATE;
#pragma unroll
  for (int n = 0; n < D_STATE; n++) {
    a2[n] = A2[d * D_STATE + n];
    h[n] = cH[base + n];
  }
  float Dd = Dvec[d];
  int rowbase = b * SEQLEN + c * CHUNKLEN;
  for (int l = 0; l < CHUNKLEN; l++) {
    int row = rowbase + l;
    float dtv = dtyg[(size_t)row * D_INNER + d];
    float xv = xi[(size_t)row * D_INNER + d];
    float dtx = dtv * xv;
    const float* Bp = xdbl + (size_t)row * 96 + 64;
    const float* Cp = Bp + D_STATE;
    float y = Dd * xv;
#pragma unroll
    for (int n = 0; n < D_STATE; n++) {
      float dA = __expf(dtv * a2[n]);
      h[n] = fmaf(dA, h[n], dtx * Bp[n]);
      y = fmaf(h[n], Cp[n], y);
    }
    float z = xz[(size_t)row * 4096 + D_INNER + d];
    dtyg[(size_t)row * D_INNER + d] = y * siluf(z);
  }
}

// ---------------------------------------------------------------------------
extern "C" void kernel_launch(void* const* d_in, const int* in_sizes, int n_in,
                              void* d_out, int out_size, void* d_ws,
                              size_t ws_size, hipStream_t stream)
{
  const float* x     = (const float*)d_in[0];
  const float* W_in  = (const float*)d_in[1];
  const float* cw    = (const float*)d_in[2];
  const float* cb    = (const float*)d_in[3];
  const float* W_x   = (const float*)d_in[4];
  const float* W_dt  = (const float*)d_in[5];
  const float* b_dt  = (const float*)d_in[6];
  const float* A_log = (const float*)d_in[7];
  const float* Dv    = (const float*)d_in[8];
  const float* W_out = (const float*)d_in[9];
  float* out = (float*)d_out;

  float* ws    = (float*)d_ws;
  float* xz    = ws;                       // 16,777,216
  float* xi    = xz + 16777216;            //  8,388,608
  float* xdbl  = xi + 8388608;             //    393,216
  float* dtyg  = xdbl + 393216;            //  8,388,608
  float* A2    = dtyg + 8388608;           //     32,768
  float* cP    = A2 + 32768;               //  2,097,152
  float* cH    = cP + 2097152;             //  2,097,152

  // packed hi/lo bf16 + partial overlays
  unsigned* WinTP  = (unsigned*)dtyg;                 // GEMM1 B (dead after)
  unsigned* xP     = (unsigned*)(dtyg + 4194304);     // GEMM1 A (dead after)
  unsigned* xiP    = (unsigned*)dtyg;                 // xdbl-GEMM A (dead after)
  unsigned* WxTP   = (unsigned*)xdbl;                 // xdbl-GEMM B (dead before reduce)
  float*    Ppart  = cP;                              // [8][4096][96] spans cP+cH
  unsigned* ygP    = (unsigned*)xi;                   // GEMM2 A (xi dead post-scan)
  unsigned* WoutTP = (unsigned*)cP;                   // GEMM2 B (cP dead post-pass2)

  aprep_k<<<128, 256, 0, stream>>>(A_log, A2);

  // W_in (1024x4096) -> transposed+packed WinTP; x -> packed xP
  transpack_k<<<dim3(16, 32), 256, 0, stream>>>(W_in, WinTP, 1024, 4096);
  packsplit_k<<<512, 256, 0, stream>>>(x, xP);

  // xz = x @ W_in   (4096x4096, K=1024)
  mgemm_split<<<dim3(32, 32), 256, 0, stream>>>(
      (const unsigned short*)xP, (const unsigned short*)WinTP, xz,
      4096, 4096, 1024, 4096);

  conv_silu_k<<<32768, 256, 0, stream>>>(xz, cw, cb, xi);

  // x_dbl = xi @ W_x via packed split-bf16 MFMA, split-K=8, private partials
  packsplit_k<<<1024, 256, 0, stream>>>(xi, xiP);
  transpack_wx_k<<<64, 128, 0, stream>>>(W_x, WxTP);
  xdbl_mfma_k<<<dim3(8, 32), 256, 0, stream>>>(
      (const unsigned short*)xiP, (const unsigned short*)WxTP, Ppart);
  xdbl_reduce_k<<<1536, 256, 0, stream>>>(Ppart, xdbl);

  // dt = softplus(x_dbl[:, :64] @ W_dt + b_dt)  (K=64, fp32)
  sgemm_k<1><<<dim3(16, 32), 256, 0, stream>>>(xdbl, W_dt, b_dt, dtyg,
                                               4096, 2048, 64, 96, 2048, 2048);

  scan_pass1<<<dim3(8, NCHUNK, NBATCH), 256, 0, stream>>>(dtyg, xi, xdbl, A2, cP, cH);
  scan_pass2<<<256, 256, 0, stream>>>(cP, cH);
  scan_pass3<<<dim3(8, NCHUNK, NBATCH), 256, 0, stream>>>(dtyg, xi, xdbl, A2, cH, Dv, xz);

  // yg -> packed; W_out -> transposed+packed
  packsplit_k<<<1024, 256, 0, stream>>>(dtyg, ygP);
  transpack_k<<<dim3(4, 64), 256, 0, stream>>>(W_out, WoutTP, 2048, 1024);

  // out = yg @ W_out  (4096x1024, K=2048)
  mgemm_split<<<dim3(8, 32), 256, 0, stream>>>(
      (const unsigned short*)ygP, (const unsigned short*)WoutTP, out,
      4096, 1024, 2048, 1024);
}